// Round 3
// baseline (288.302 us; speedup 1.0000x reference)
//
#include <hip/hip_runtime.h>
#include <hip/hip_bf16.h>
#include <type_traits>

typedef __bf16 bf16x8 __attribute__((ext_vector_type(8)));
typedef float floatx4 __attribute__((ext_vector_type(4)));

#define S_LEN 2048
#define D_DIM 128
#define NTOK (2 * 16 * 2048)  // B*H*S = 65536 rows
#define KVB 64
#define NKV (S_LEN / KVB)     // 32 kv tiles

// ---------------------------------------------------------------------------
// proj_kernel: y[r,e] = (sum_d x[r,d] * W[e,d] + b[e]) * out_scale
// ---------------------------------------------------------------------------
template <typename TIN, typename TOUT>
__global__ __launch_bounds__(256) void proj_kernel(
    const TIN* __restrict__ x, const float* __restrict__ W,
    const float* __restrict__ b, TOUT* __restrict__ y, float out_scale) {
  __shared__ alignas(16) __bf16 Wl[128][128];  // 32 KB

  const int tid = threadIdx.x;
  const int wave = tid >> 6, lane = tid & 63;
  const int g = lane >> 4, lr = lane & 15;

  for (int it = 0; it < 16; ++it) {
    int lin = it * 1024 + tid * 4;
    float4 w4 = *reinterpret_cast<const float4*>(W + lin);
    int r = lin >> 7, c = lin & 127;
    Wl[r][c]     = (__bf16)w4.x;
    Wl[r][c + 1] = (__bf16)w4.y;
    Wl[r][c + 2] = (__bf16)w4.z;
    Wl[r][c + 3] = (__bf16)w4.w;
  }
  __syncthreads();

  const int rbase = blockIdx.x * 64;
  const int arow = rbase + wave * 16 + lr;

  floatx4 acc[8];
  for (int i = 0; i < 8; ++i) acc[i] = floatx4{0.f, 0.f, 0.f, 0.f};

  for (int kc = 0; kc < 4; ++kc) {
    bf16x8 af;
    const TIN* xp = x + (size_t)arow * D_DIM + kc * 32 + g * 8;
    if constexpr (std::is_same<TIN, float>::value) {
      float4 f0 = *reinterpret_cast<const float4*>(xp);
      float4 f1 = *reinterpret_cast<const float4*>(xp + 4);
      af[0] = (__bf16)f0.x; af[1] = (__bf16)f0.y;
      af[2] = (__bf16)f0.z; af[3] = (__bf16)f0.w;
      af[4] = (__bf16)f1.x; af[5] = (__bf16)f1.y;
      af[6] = (__bf16)f1.z; af[7] = (__bf16)f1.w;
    } else {
      af = *reinterpret_cast<const bf16x8*>(xp);
    }
    for (int nt = 0; nt < 8; ++nt) {
      bf16x8 wf = *reinterpret_cast<const bf16x8*>(&Wl[nt * 16 + lr][kc * 32 + g * 8]);
      acc[nt] = __builtin_amdgcn_mfma_f32_16x16x32_bf16(af, wf, acc[nt], 0, 0, 0);
    }
  }

  for (int nt = 0; nt < 8; ++nt) {
    int e = nt * 16 + lr;
    float be = b[e];
    for (int j = 0; j < 4; ++j) {
      int row = rbase + wave * 16 + g * 4 + j;
      float val = (acc[nt][j] + be) * out_scale;
      y[(size_t)row * D_DIM + e] = (TOUT)val;
    }
  }
}

// ---------------------------------------------------------------------------
// LDS XOR swizzle: flips byte-offset bits 4..6 by (row ^ row>>3) & 7.
// Bijective within each 128B-aligned row; preserves 16B alignment.
// ---------------------------------------------------------------------------
__device__ __forceinline__ unsigned swz(int row, unsigned byteoff) {
  return byteoff ^ (((unsigned)(row ^ (row >> 3)) & 7u) << 4);
}

// ---------------------------------------------------------------------------
// attn_kernel v3: flash attention, 8 waves x 32 Q-rows = 256 q-rows/block.
// KVB=64. K/V double-buffered in LDS (async-split staging: global loads for
// tile t+1 issued before compute on tile t, LDS writes after). One barrier
// per kv-tile:
//   iter t reads buf[cur], then writes buf[nxt];
//   iter t+1's top barrier separates (a) t's nxt-writes from t+1's nxt-reads
//   and (b) t's cur-reads from t+1's end-writes to that same buffer.
// Every K/V/P LDS fragment feeds 2 MFMAs (2 q-row-tiles) -> 2x FLOP/LDS-byte
// vs round 2. Grid (bh=32, qchunk=8): linear id % 8 == bh % 8 -> all 8
// q-blocks of a head land on one XCD; 4 heads/XCD = 4 MB K+V = L2 size.
// LDS = 32 (Kx2) + 32 (Vtx2) + 32 (P) = 96 KB -> 1 block/CU, 2 waves/SIMD.
// ---------------------------------------------------------------------------
__global__ __launch_bounds__(512, 2) void attn_kernel(
    const __bf16* __restrict__ q, const __bf16* __restrict__ k,
    const __bf16* __restrict__ v, __bf16* __restrict__ o) {
  __shared__ alignas(16) unsigned char Klb[2][64 * 256];    // 32 KB
  __shared__ alignas(16) unsigned char Vtb[2][128 * 128];   // 32 KB
  __shared__ alignas(16) unsigned char Plb[8][32 * 128];    // 32 KB

  const int tid = threadIdx.x;
  const int wave = tid >> 6, lane = tid & 63;
  const int g = lane >> 4, lr = lane & 15;

  const int bh = blockIdx.x;            // 0..31
  const int qbase = blockIdx.y * 256;   // 0..7 chunks
  const __bf16* qp = q + (size_t)bh * S_LEN * D_DIM;
  const __bf16* kp = k + (size_t)bh * S_LEN * D_DIM;
  const __bf16* vp = v + (size_t)bh * S_LEN * D_DIM;

  // Q fragments: 2 row-tiles x 4 k-chunks (A layout: row=lane&15, k=g*8+i)
  bf16x8 qf[2][4];
  for (int rt = 0; rt < 2; ++rt) {
    int qrow = qbase + wave * 32 + rt * 16 + lr;
    for (int kc = 0; kc < 4; ++kc)
      qf[rt][kc] = *reinterpret_cast<const bf16x8*>(
          qp + (size_t)qrow * D_DIM + kc * 32 + g * 8);
  }

  floatx4 acc[2][8];
  for (int rt = 0; rt < 2; ++rt)
    for (int dt = 0; dt < 8; ++dt) acc[rt][dt] = floatx4{0.f, 0.f, 0.f, 0.f};
  float m_r[2][4], l_r[2][4];
  for (int rt = 0; rt < 2; ++rt)
    for (int j = 0; j < 4; ++j) { m_r[rt][j] = -1e30f; l_r[rt][j] = 0.f; }

  // staging map: 512 thr; group-row sr = tid>>4 (0..31), col sc = (tid&15)*8.
  // Each thread stages rows {sr, sr+32} of K and V.
  const int sr = tid >> 4;
  const int sc = (tid & 15) * 8;

  // prologue: stage tile 0 into buf 0
  {
    bf16x8 k0 = *reinterpret_cast<const bf16x8*>(kp + (size_t)sr * D_DIM + sc);
    bf16x8 k1 = *reinterpret_cast<const bf16x8*>(kp + (size_t)(sr + 32) * D_DIM + sc);
    bf16x8 v0 = *reinterpret_cast<const bf16x8*>(vp + (size_t)sr * D_DIM + sc);
    bf16x8 v1 = *reinterpret_cast<const bf16x8*>(vp + (size_t)(sr + 32) * D_DIM + sc);
    *reinterpret_cast<bf16x8*>(Klb[0] + swz(sr, sr * 256u + sc * 2u)) = k0;
    *reinterpret_cast<bf16x8*>(Klb[0] + swz(sr + 32, (sr + 32) * 256u + sc * 2u)) = k1;
    for (int e = 0; e < 8; ++e) {
      int vr0 = sc + e;
      *reinterpret_cast<__bf16*>(Vtb[0] + swz(vr0, vr0 * 128u + sr * 2u)) = v0[e];
      *reinterpret_cast<__bf16*>(Vtb[0] + swz(vr0, vr0 * 128u + (sr + 32) * 2u)) = v1[e];
    }
  }

  for (int t = 0; t < NKV; ++t) {
    const int cur = t & 1;
    const bool hn = (t + 1 < NKV);
    bf16x8 kn0, kn1, vn0, vn1;
    if (hn) {  // issue next-tile loads early; latency hides under compute
      size_t base = (size_t)(t + 1) * KVB;
      kn0 = *reinterpret_cast<const bf16x8*>(kp + (base + sr) * D_DIM + sc);
      kn1 = *reinterpret_cast<const bf16x8*>(kp + (base + sr + 32) * D_DIM + sc);
      vn0 = *reinterpret_cast<const bf16x8*>(vp + (base + sr) * D_DIM + sc);
      vn1 = *reinterpret_cast<const bf16x8*>(vp + (base + sr + 32) * D_DIM + sc);
    }
    __syncthreads();  // buf[cur] staged; prev readers done (see header comment)

    // ---- QK^T: each kf fragment feeds both row-tiles ----
    floatx4 s[2][4];
    for (int rt = 0; rt < 2; ++rt)
      for (int nt = 0; nt < 4; ++nt) s[rt][nt] = floatx4{0.f, 0.f, 0.f, 0.f};
    for (int nt = 0; nt < 4; ++nt) {
      for (int kc = 0; kc < 4; ++kc) {
        int row = nt * 16 + lr;
        bf16x8 kf = *reinterpret_cast<const bf16x8*>(
            Klb[cur] + swz(row, row * 256u + (kc * 32u + g * 8u) * 2u));
        s[0][nt] = __builtin_amdgcn_mfma_f32_16x16x32_bf16(qf[0][kc], kf, s[0][nt], 0, 0, 0);
        s[1][nt] = __builtin_amdgcn_mfma_f32_16x16x32_bf16(qf[1][kc], kf, s[1][nt], 0, 0, 0);
      }
    }

    // ---- online softmax (rows: rt*16 + g*4 + j, cols: nt*16 + lr) ----
    float scale[2][4];
    for (int rt = 0; rt < 2; ++rt)
      for (int j = 0; j < 4; ++j) {
        float mx = fmaxf(fmaxf(s[rt][0][j], s[rt][1][j]),
                         fmaxf(s[rt][2][j], s[rt][3][j]));
        mx = fmaxf(mx, __shfl_xor(mx, 1));
        mx = fmaxf(mx, __shfl_xor(mx, 2));
        mx = fmaxf(mx, __shfl_xor(mx, 4));
        mx = fmaxf(mx, __shfl_xor(mx, 8));
        float mnew = fmaxf(m_r[rt][j], mx);
        scale[rt][j] = __expf(m_r[rt][j] - mnew);
        m_r[rt][j] = mnew;
        float psum = 0.f;
        for (int nt = 0; nt < 4; ++nt) {
          float p = __expf(s[rt][nt][j] - mnew);
          s[rt][nt][j] = p;
          psum += p;
        }
        psum += __shfl_xor(psum, 1);
        psum += __shfl_xor(psum, 2);
        psum += __shfl_xor(psum, 4);
        psum += __shfl_xor(psum, 8);
        l_r[rt][j] = l_r[rt][j] * scale[rt][j] + psum;
      }

    // rescale O
    for (int rt = 0; rt < 2; ++rt)
      for (int dt = 0; dt < 8; ++dt)
        for (int j = 0; j < 4; ++j) acc[rt][dt][j] *= scale[rt][j];

    // ---- P: C-layout -> per-wave LDS [q_local 32][kv 64] (swizzled) ----
    for (int rt = 0; rt < 2; ++rt)
      for (int nt = 0; nt < 4; ++nt)
        for (int j = 0; j < 4; ++j) {
          int prow = rt * 16 + g * 4 + j;
          *reinterpret_cast<__bf16*>(
              Plb[wave] + swz(prow, prow * 128u + (nt * 16u + lr) * 2u)) =
              (__bf16)s[rt][nt][j];
        }

    // ---- PV: each vf fragment feeds both row-tiles ----
    for (int cc = 0; cc < 2; ++cc) {
      bf16x8 pf[2];
      for (int rt = 0; rt < 2; ++rt) {
        int prow = rt * 16 + lr;
        pf[rt] = *reinterpret_cast<const bf16x8*>(
            Plb[wave] + swz(prow, prow * 128u + (cc * 32u + g * 8u) * 2u));
      }
      for (int dt = 0; dt < 8; ++dt) {
        int vrow = dt * 16 + lr;
        bf16x8 vf = *reinterpret_cast<const bf16x8*>(
            Vtb[cur] + swz(vrow, vrow * 128u + (cc * 32u + g * 8u) * 2u));
        acc[0][dt] = __builtin_amdgcn_mfma_f32_16x16x32_bf16(pf[0], vf, acc[0][dt], 0, 0, 0);
        acc[1][dt] = __builtin_amdgcn_mfma_f32_16x16x32_bf16(pf[1], vf, acc[1][dt], 0, 0, 0);
      }
    }

    // ---- write staged tile t+1 into buf[nxt] ----
    if (hn) {
      const int nxt = cur ^ 1;
      *reinterpret_cast<bf16x8*>(Klb[nxt] + swz(sr, sr * 256u + sc * 2u)) = kn0;
      *reinterpret_cast<bf16x8*>(Klb[nxt] + swz(sr + 32, (sr + 32) * 256u + sc * 2u)) = kn1;
      for (int e = 0; e < 8; ++e) {
        int vr0 = sc + e;
        *reinterpret_cast<__bf16*>(Vtb[nxt] + swz(vr0, vr0 * 128u + sr * 2u)) = vn0[e];
        *reinterpret_cast<__bf16*>(Vtb[nxt] + swz(vr0, vr0 * 128u + (sr + 32) * 2u)) = vn1[e];
      }
    }
  }

  // epilogue: O / l, write bf16
  for (int rt = 0; rt < 2; ++rt) {
    float inv_l[4];
    for (int j = 0; j < 4; ++j) inv_l[j] = 1.0f / l_r[rt][j];
    for (int dt = 0; dt < 8; ++dt)
      for (int j = 0; j < 4; ++j) {
        int row = qbase + wave * 32 + rt * 16 + g * 4 + j;
        o[((size_t)bh * S_LEN + row) * D_DIM + dt * 16 + lr] =
            (__bf16)(acc[rt][dt][j] * inv_l[j]);
      }
  }
}

// ---------------------------------------------------------------------------
extern "C" void kernel_launch(void* const* d_in, const int* in_sizes, int n_in,
                              void* d_out, int out_size, void* d_ws, size_t ws_size,
                              hipStream_t stream) {
  const float* query = (const float*)d_in[0];
  const float* key_  = (const float*)d_in[1];
  const float* value = (const float*)d_in[2];
  const float* Wq = (const float*)d_in[3];
  const float* bq = (const float*)d_in[4];
  const float* Wk = (const float*)d_in[5];
  const float* bk = (const float*)d_in[6];
  const float* Wv = (const float*)d_in[7];
  const float* bv = (const float*)d_in[8];
  const float* Wo = (const float*)d_in[9];
  const float* bo = (const float*)d_in[10];

  // scratch layout: v + attn-out in d_ws (33.5 MB); q + k scratch inside d_out
  // (bf16, fully overwritten by the final fp32 projection)
  __bf16* vws = (__bf16*)d_ws;
  __bf16* aws = vws + (size_t)NTOK * D_DIM;
  __bf16* qws = (__bf16*)d_out;
  __bf16* kws = qws + (size_t)NTOK * D_DIM;

  const float qscale = 0.08838834764831845f;  // 1/sqrt(128)

  dim3 blk(256);
  proj_kernel<float, __bf16><<<NTOK / 64, blk, 0, stream>>>(query, Wq, bq, qws, qscale);
  proj_kernel<float, __bf16><<<NTOK / 64, blk, 0, stream>>>(key_, Wk, bk, kws, 1.0f);
  proj_kernel<float, __bf16><<<NTOK / 64, blk, 0, stream>>>(value, Wv, bv, vws, 1.0f);

  attn_kernel<<<dim3(32, 8), dim3(512), 0, stream>>>(qws, kws, vws, aws);

  proj_kernel<__bf16, float><<<NTOK / 64, blk, 0, stream>>>(aws, Wo, bo, (float*)d_out, 1.0f);
}

// Round 4
// 175.363 us; speedup vs baseline: 1.6440x; 1.6440x over previous
//
#include <hip/hip_runtime.h>
#include <hip/hip_bf16.h>
#include <type_traits>

typedef __bf16 bf16x8 __attribute__((ext_vector_type(8)));
typedef float floatx4 __attribute__((ext_vector_type(4)));
typedef float floatx16 __attribute__((ext_vector_type(16)));

#define S_LEN 2048
#define D_DIM 128
#define NTOK (2 * 16 * 2048)  // B*H*S = 65536 rows
#define KVB 64
#define NKV (S_LEN / KVB)     // 32 kv tiles

// ---------------------------------------------------------------------------
// proj_kernel: y[r,e] = (sum_d x[r,d] * W[e,d] + b[e]) * out_scale
// ---------------------------------------------------------------------------
template <typename TIN, typename TOUT>
__global__ __launch_bounds__(256) void proj_kernel(
    const TIN* __restrict__ x, const float* __restrict__ W,
    const float* __restrict__ b, TOUT* __restrict__ y, float out_scale) {
  __shared__ alignas(16) __bf16 Wl[128][128];  // 32 KB

  const int tid = threadIdx.x;
  const int wave = tid >> 6, lane = tid & 63;
  const int g = lane >> 4, lr = lane & 15;

  for (int it = 0; it < 16; ++it) {
    int lin = it * 1024 + tid * 4;
    float4 w4 = *reinterpret_cast<const float4*>(W + lin);
    int r = lin >> 7, c = lin & 127;
    Wl[r][c]     = (__bf16)w4.x;
    Wl[r][c + 1] = (__bf16)w4.y;
    Wl[r][c + 2] = (__bf16)w4.z;
    Wl[r][c + 3] = (__bf16)w4.w;
  }
  __syncthreads();

  const int rbase = blockIdx.x * 64;
  const int arow = rbase + wave * 16 + lr;

  floatx4 acc[8];
  for (int i = 0; i < 8; ++i) acc[i] = floatx4{0.f, 0.f, 0.f, 0.f};

  for (int kc = 0; kc < 4; ++kc) {
    bf16x8 af;
    const TIN* xp = x + (size_t)arow * D_DIM + kc * 32 + g * 8;
    if constexpr (std::is_same<TIN, float>::value) {
      float4 f0 = *reinterpret_cast<const float4*>(xp);
      float4 f1 = *reinterpret_cast<const float4*>(xp + 4);
      af[0] = (__bf16)f0.x; af[1] = (__bf16)f0.y;
      af[2] = (__bf16)f0.z; af[3] = (__bf16)f0.w;
      af[4] = (__bf16)f1.x; af[5] = (__bf16)f1.y;
      af[6] = (__bf16)f1.z; af[7] = (__bf16)f1.w;
    } else {
      af = *reinterpret_cast<const bf16x8*>(xp);
    }
    for (int nt = 0; nt < 8; ++nt) {
      bf16x8 wf = *reinterpret_cast<const bf16x8*>(&Wl[nt * 16 + lr][kc * 32 + g * 8]);
      acc[nt] = __builtin_amdgcn_mfma_f32_16x16x32_bf16(af, wf, acc[nt], 0, 0, 0);
    }
  }

  for (int nt = 0; nt < 8; ++nt) {
    int e = nt * 16 + lr;
    float be = b[e];
    for (int j = 0; j < 4; ++j) {
      int row = rbase + wave * 16 + g * 4 + j;
      float val = (acc[nt][j] + be) * out_scale;
      y[(size_t)row * D_DIM + e] = (TOUT)val;
    }
  }
}

// ---------------------------------------------------------------------------
// LDS XOR swizzle: flips byte-offset bits 4..6 by (row ^ row>>3) & 7.
// Bijective within each row; preserves 16B alignment.
// ---------------------------------------------------------------------------
__device__ __forceinline__ unsigned swz(int row, unsigned byteoff) {
  return byteoff ^ (((unsigned)(row ^ (row >> 3)) & 7u) << 4);
}

__device__ __forceinline__ unsigned pack2(float lo, float hi) {
  union { __bf16 h[2]; unsigned u; } r;
  r.h[0] = (__bf16)lo; r.h[1] = (__bf16)hi;
  return r.u;
}

// ---------------------------------------------------------------------------
// attn_kernel v4 (m214-style): 8 waves x 32 q-rows, KVB=64, 32x32x16 MFMA.
// Swapped QK^T: S^T = mfma(A=K, B=Q^T). C-layout (verified m74/m101):
//   col = lane&31 (= q), row = (reg&3) + 8*(reg>>2) + 4*(lane>>5) (= kv-local)
// -> each lane holds 32 S values of ONE q-row; lanes l and l^32 share q and
// hold complementary kv offsets (h=lane>>5 holds group-offsets 4h..4h+3 of
// each 8-kv group). Softmax fully in-register (m,l scalar per lane).
// PV: O^T = mfma(A=V^T, B=P^T). P^T B-fragments assembled in-register:
//   frag(ks) element i needs kv = ks*16 + h*8 + i, i.e. 8-kv group G=2ks+h:
//   offsets 0-3 live in the h=0 partner's reg-quad r2=G&3 of st[G>>2],
//   offsets 4-7 in the h=1 partner's same quad -> pack quads r2=(2ks)&3 and
//   (2ks)|1, __shfl_xor(32), select by h. No P LDS at all.
// K/V double-buffered (async reg staging, 1 barrier/tile). LDS 64 KB, union'd
// with a 64 KB epilogue buffer for coalesced O stores.
// Grid (bh=32, qchunk=8): XCD = linear%8 = bh%8 -> 4 heads/XCD in L2.
// ---------------------------------------------------------------------------
__global__ __launch_bounds__(512, 2) void attn_kernel(
    const __bf16* __restrict__ q, const __bf16* __restrict__ k,
    const __bf16* __restrict__ v, __bf16* __restrict__ o) {
  __shared__ alignas(16) unsigned char smem[65536];
  unsigned char* Klb = smem;            // [2][64 rows * 256 B]  (32 KB)
  unsigned char* Vtb = smem + 32768;    // [2][128 rows * 128 B] (32 KB)

  const int tid = threadIdx.x;
  const int wave = tid >> 6, lane = tid & 63;
  const int ql = lane & 31;   // A-row and B-col index (m = n = lane&31)
  const int h = lane >> 5;    // k-slice half

  const int bh = blockIdx.x;
  const int qbase = blockIdx.y * 256;
  const __bf16* qp = q + (size_t)bh * S_LEN * D_DIM;
  const __bf16* kp = k + (size_t)bh * S_LEN * D_DIM;
  const __bf16* vp = v + (size_t)bh * S_LEN * D_DIM;
  __bf16* op = o + (size_t)bh * S_LEN * D_DIM;

  // Q^T B-fragments: lane needs Q[qrow][kc*16 + h*8 + i], qrow = base + ql
  const int qrow = qbase + wave * 32 + ql;
  bf16x8 qf[8];
#pragma unroll
  for (int kc = 0; kc < 8; ++kc)
    qf[kc] = *reinterpret_cast<const bf16x8*>(
        qp + (size_t)qrow * D_DIM + kc * 16 + h * 8);

  floatx16 ot[4];  // O^T accumulator: 4 d-blocks of 32 rows
#pragma unroll
  for (int d = 0; d < 4; ++d)
#pragma unroll
    for (int r = 0; r < 16; ++r) ot[d][r] = 0.f;
  float m_r = -1e30f, l_r = 0.f;

  // staging map: sr = tid>>4 (0..31), sc = (tid&15)*8; rows {sr, sr+32}
  const int sr = tid >> 4;
  const int sc = (tid & 15) * 8;

  // prologue: stage tile 0 into buf 0
  {
    bf16x8 k0 = *reinterpret_cast<const bf16x8*>(kp + (size_t)sr * D_DIM + sc);
    bf16x8 k1 = *reinterpret_cast<const bf16x8*>(kp + (size_t)(sr + 32) * D_DIM + sc);
    bf16x8 v0 = *reinterpret_cast<const bf16x8*>(vp + (size_t)sr * D_DIM + sc);
    bf16x8 v1 = *reinterpret_cast<const bf16x8*>(vp + (size_t)(sr + 32) * D_DIM + sc);
    *reinterpret_cast<bf16x8*>(Klb + swz(sr, sr * 256u + sc * 2u)) = k0;
    *reinterpret_cast<bf16x8*>(Klb + swz(sr + 32, (sr + 32) * 256u + sc * 2u)) = k1;
#pragma unroll
    for (int e = 0; e < 8; ++e) {
      int vr = sc + e;
      *reinterpret_cast<__bf16*>(Vtb + swz(vr, vr * 128u + sr * 2u)) = v0[e];
      *reinterpret_cast<__bf16*>(Vtb + swz(vr, vr * 128u + (sr + 32) * 2u)) = v1[e];
    }
  }

  for (int t = 0; t < NKV; ++t) {
    const unsigned cb = (unsigned)(t & 1) * 16384u;
    const bool hn = (t + 1 < NKV);
    bf16x8 kn0, kn1, vn0, vn1;
    if (hn) {  // issue next-tile global loads; latency hides under compute
      size_t base = (size_t)(t + 1) * KVB;
      kn0 = *reinterpret_cast<const bf16x8*>(kp + (base + sr) * D_DIM + sc);
      kn1 = *reinterpret_cast<const bf16x8*>(kp + (base + sr + 32) * D_DIM + sc);
      vn0 = *reinterpret_cast<const bf16x8*>(vp + (base + sr) * D_DIM + sc);
      vn1 = *reinterpret_cast<const bf16x8*>(vp + (base + sr + 32) * D_DIM + sc);
    }
    __syncthreads();  // buf[cur] staged; previous tile's readers done

    // ---- QK^T: S^T[kv][q], kv in 2 halves of 32, d accumulated over 8 kc ----
    floatx16 st[2];
#pragma unroll
    for (int kvh = 0; kvh < 2; ++kvh)
#pragma unroll
      for (int r = 0; r < 16; ++r) st[kvh][r] = 0.f;
#pragma unroll
    for (int kvh = 0; kvh < 2; ++kvh) {
#pragma unroll
      for (int kc = 0; kc < 8; ++kc) {
        int row = kvh * 32 + ql;  // A-row: K row = kv
        bf16x8 kf = *reinterpret_cast<const bf16x8*>(
            Klb + cb + swz(row, row * 256u + kc * 32u + h * 16u));
        st[kvh] = __builtin_amdgcn_mfma_f32_32x32x16_bf16(kf, qf[kc], st[kvh], 0, 0, 0);
      }
    }

    // ---- softmax in-register (q = lane&31; partner lane^32 shares q) ----
    float pmax = st[0][0];
#pragma unroll
    for (int kvh = 0; kvh < 2; ++kvh)
#pragma unroll
      for (int r = 0; r < 16; ++r) pmax = fmaxf(pmax, st[kvh][r]);
    pmax = fmaxf(pmax, __shfl_xor(pmax, 32));
    float mnew = fmaxf(m_r, pmax);
    float sc_f = __expf(m_r - mnew);
    m_r = mnew;
    float psum = 0.f;
#pragma unroll
    for (int kvh = 0; kvh < 2; ++kvh)
#pragma unroll
      for (int r = 0; r < 16; ++r) {
        float p = __expf(st[kvh][r] - mnew);
        st[kvh][r] = p;
        psum += p;
      }
    psum += __shfl_xor(psum, 32);
    l_r = l_r * sc_f + psum;
#pragma unroll
    for (int d = 0; d < 4; ++d)
#pragma unroll
      for (int r = 0; r < 16; ++r) ot[d][r] *= sc_f;

    // ---- P^T B-fragments in-register + PV ----
#pragma unroll
    for (int ks = 0; ks < 4; ++ks) {
      const int kvh = ks >> 1;
      const int r2a = (2 * ks) & 3;   // quad for group G=2ks
      const int r2b = r2a + 1;        // quad for group G=2ks+1
      unsigned a0 = pack2(st[kvh][r2a * 4 + 0], st[kvh][r2a * 4 + 1]);
      unsigned a1 = pack2(st[kvh][r2a * 4 + 2], st[kvh][r2a * 4 + 3]);
      unsigned b0 = pack2(st[kvh][r2b * 4 + 0], st[kvh][r2b * 4 + 1]);
      unsigned b1 = pack2(st[kvh][r2b * 4 + 2], st[kvh][r2b * 4 + 3]);
      unsigned a0x = __shfl_xor(a0, 32), a1x = __shfl_xor(a1, 32);
      unsigned b0x = __shfl_xor(b0, 32), b1x = __shfl_xor(b1, 32);
      union { unsigned u[4]; bf16x8 v8; } pw;
      pw.u[0] = h ? b0x : a0;   // kv offsets 0-1 of group 2ks+h
      pw.u[1] = h ? b1x : a1;   // offsets 2-3
      pw.u[2] = h ? b0 : a0x;   // offsets 4-5
      pw.u[3] = h ? b1 : a1x;   // offsets 6-7
#pragma unroll
      for (int db = 0; db < 4; ++db) {
        int row = db * 32 + ql;  // A-row: V^T row = d
        bf16x8 vf = *reinterpret_cast<const bf16x8*>(
            Vtb + cb + swz(row, row * 128u + ks * 32u + h * 16u));
        ot[db] = __builtin_amdgcn_mfma_f32_32x32x16_bf16(vf, pw.v8, ot[db], 0, 0, 0);
      }
    }

    // ---- write staged tile t+1 into buf[nxt] ----
    if (hn) {
      const unsigned nb = cb ^ 16384u;
      *reinterpret_cast<bf16x8*>(Klb + nb + swz(sr, sr * 256u + sc * 2u)) = kn0;
      *reinterpret_cast<bf16x8*>(Klb + nb + swz(sr + 32, (sr + 32) * 256u + sc * 2u)) = kn1;
#pragma unroll
      for (int e = 0; e < 8; ++e) {
        int vr = sc + e;
        *reinterpret_cast<__bf16*>(Vtb + nb + swz(vr, vr * 128u + sr * 2u)) = vn0[e];
        *reinterpret_cast<__bf16*>(Vtb + nb + swz(vr, vr * 128u + (sr + 32) * 2u)) = vn1[e];
      }
    }
  }

  // ---- epilogue: O^T -> LDS (transpose) -> coalesced global stores ----
  __syncthreads();  // all waves done with K/V LDS; reuse as O tile [256][128]
  const float inv_l = 1.0f / l_r;
  const int qloc = wave * 32 + ql;
#pragma unroll
  for (int db = 0; db < 4; ++db)
#pragma unroll
    for (int r = 0; r < 16; ++r) {
      int d = db * 32 + (r & 3) + 8 * (r >> 2) + 4 * h;
      *reinterpret_cast<__bf16*>(smem + swz(qloc, qloc * 256u + d * 2u)) =
          (__bf16)(ot[db][r] * inv_l);
    }
  __syncthreads();
#pragma unroll
  for (int it = 0; it < 8; ++it) {
    int r = tid >> 1;                  // 0..255
    int c = (tid & 1) * 64 + it * 8;   // element col
    bf16x8 val = *reinterpret_cast<const bf16x8*>(smem + swz(r, r * 256u + c * 2u));
    *reinterpret_cast<bf16x8*>(op + (size_t)(qbase + r) * D_DIM + c) = val;
  }
}

// ---------------------------------------------------------------------------
extern "C" void kernel_launch(void* const* d_in, const int* in_sizes, int n_in,
                              void* d_out, int out_size, void* d_ws, size_t ws_size,
                              hipStream_t stream) {
  const float* query = (const float*)d_in[0];
  const float* key_  = (const float*)d_in[1];
  const float* value = (const float*)d_in[2];
  const float* Wq = (const float*)d_in[3];
  const float* bq = (const float*)d_in[4];
  const float* Wk = (const float*)d_in[5];
  const float* bk = (const float*)d_in[6];
  const float* Wv = (const float*)d_in[7];
  const float* bv = (const float*)d_in[8];
  const float* Wo = (const float*)d_in[9];
  const float* bo = (const float*)d_in[10];

  // scratch: v + attn-out in d_ws; q + k scratch inside d_out (bf16, fully
  // overwritten by the final fp32 projection)
  __bf16* vws = (__bf16*)d_ws;
  __bf16* aws = vws + (size_t)NTOK * D_DIM;
  __bf16* qws = (__bf16*)d_out;
  __bf16* kws = qws + (size_t)NTOK * D_DIM;

  const float qscale = 0.08838834764831845f;  // 1/sqrt(128)

  dim3 blk(256);
  proj_kernel<float, __bf16><<<NTOK / 64, blk, 0, stream>>>(query, Wq, bq, qws, qscale);
  proj_kernel<float, __bf16><<<NTOK / 64, blk, 0, stream>>>(key_, Wk, bk, kws, 1.0f);
  proj_kernel<float, __bf16><<<NTOK / 64, blk, 0, stream>>>(value, Wv, bv, vws, 1.0f);

  attn_kernel<<<dim3(32, 8), dim3(512), 0, stream>>>(qws, kws, vws, aws);

  proj_kernel<__bf16, float><<<NTOK / 64, blk, 0, stream>>>(aws, Wo, bo, (float*)d_out, 1.0f);
}

// Round 5
// 163.351 us; speedup vs baseline: 1.7649x; 1.0735x over previous
//
#include <hip/hip_runtime.h>
#include <hip/hip_bf16.h>
#include <type_traits>
#include <math.h>

typedef __bf16 bf16x8 __attribute__((ext_vector_type(8)));
typedef float floatx4 __attribute__((ext_vector_type(4)));
typedef float floatx16 __attribute__((ext_vector_type(16)));

#define S_LEN 2048
#define D_DIM 128
#define NTOK (2 * 16 * 2048)  // B*H*S = 65536 rows
#define KVB 64
#define NKV (S_LEN / KVB)     // 32 kv tiles

// ---------------------------------------------------------------------------
// proj_kernel: y[r,e] = (sum_d x[r,d] * W[e,d] + b[e]) * out_scale
// ---------------------------------------------------------------------------
template <typename TIN, typename TOUT>
__global__ __launch_bounds__(256) void proj_kernel(
    const TIN* __restrict__ x, const float* __restrict__ W,
    const float* __restrict__ b, TOUT* __restrict__ y, float out_scale) {
  __shared__ alignas(16) __bf16 Wl[128][128];  // 32 KB

  const int tid = threadIdx.x;
  const int wave = tid >> 6, lane = tid & 63;
  const int g = lane >> 4, lr = lane & 15;

  for (int it = 0; it < 16; ++it) {
    int lin = it * 1024 + tid * 4;
    float4 w4 = *reinterpret_cast<const float4*>(W + lin);
    int r = lin >> 7, c = lin & 127;
    Wl[r][c]     = (__bf16)w4.x;
    Wl[r][c + 1] = (__bf16)w4.y;
    Wl[r][c + 2] = (__bf16)w4.z;
    Wl[r][c + 3] = (__bf16)w4.w;
  }
  __syncthreads();

  const int rbase = blockIdx.x * 64;
  const int arow = rbase + wave * 16 + lr;

  floatx4 acc[8];
  for (int i = 0; i < 8; ++i) acc[i] = floatx4{0.f, 0.f, 0.f, 0.f};

  for (int kc = 0; kc < 4; ++kc) {
    bf16x8 af;
    const TIN* xp = x + (size_t)arow * D_DIM + kc * 32 + g * 8;
    if constexpr (std::is_same<TIN, float>::value) {
      float4 f0 = *reinterpret_cast<const float4*>(xp);
      float4 f1 = *reinterpret_cast<const float4*>(xp + 4);
      af[0] = (__bf16)f0.x; af[1] = (__bf16)f0.y;
      af[2] = (__bf16)f0.z; af[3] = (__bf16)f0.w;
      af[4] = (__bf16)f1.x; af[5] = (__bf16)f1.y;
      af[6] = (__bf16)f1.z; af[7] = (__bf16)f1.w;
    } else {
      af = *reinterpret_cast<const bf16x8*>(xp);
    }
    for (int nt = 0; nt < 8; ++nt) {
      bf16x8 wf = *reinterpret_cast<const bf16x8*>(&Wl[nt * 16 + lr][kc * 32 + g * 8]);
      acc[nt] = __builtin_amdgcn_mfma_f32_16x16x32_bf16(af, wf, acc[nt], 0, 0, 0);
    }
  }

  for (int nt = 0; nt < 8; ++nt) {
    int e = nt * 16 + lr;
    float be = b[e];
    for (int j = 0; j < 4; ++j) {
      int row = rbase + wave * 16 + g * 4 + j;
      float val = (acc[nt][j] + be) * out_scale;
      y[(size_t)row * D_DIM + e] = (TOUT)val;
    }
  }
}

// ---------------------------------------------------------------------------
// LDS XOR swizzle: flips byte-offset bits 4..6 by (row ^ row>>3) & 7.
// Bijective within each row; preserves 16B/4B alignment.
// ---------------------------------------------------------------------------
__device__ __forceinline__ unsigned swz(int row, unsigned byteoff) {
  return byteoff ^ (((unsigned)(row ^ (row >> 3)) & 7u) << 4);
}

__device__ __forceinline__ unsigned pack2(float lo, float hi) {
  union { __bf16 h[2]; unsigned u; } r;
  r.h[0] = (__bf16)lo; r.h[1] = (__bf16)hi;
  return r.u;
}

// ---------------------------------------------------------------------------
// attn_kernel v5: 4 waves x 32 q-rows = 128 q-rows/block; grid (32, 16) =
// 512 blocks = 2 INDEPENDENT blocks/CU (de-lockstep: separate barriers ->
// phase-offset pipe overlap). Swapped QK^T (32x32x16), in-register softmax
// in exp2 domain (log2e folded into q-projection scale), tree max/sum,
// T13 defer-rescale (THR=8 log2-units), P^T assembled in-register (no P LDS).
// K/V double-buffered; V staged via paired-kv b32 writes (no scalar writes).
// One barrier per kv-tile (same proof as v3/v4). LDS 64 KB/block.
// ---------------------------------------------------------------------------
__global__ __launch_bounds__(256, 2) void attn_kernel(
    const __bf16* __restrict__ q, const __bf16* __restrict__ k,
    const __bf16* __restrict__ v, __bf16* __restrict__ o) {
  __shared__ alignas(16) unsigned char smem[65536];
  unsigned char* Klb = smem;            // [2][64 rows * 256 B]  (32 KB)
  unsigned char* Vtb = smem + 32768;    // [2][128 rows * 128 B] (32 KB)

  const int tid = threadIdx.x;
  const int wave = tid >> 6, lane = tid & 63;
  const int ql = lane & 31;   // q index within wave tile (m = n = lane&31)
  const int h = lane >> 5;    // k-slice half

  const int bh = blockIdx.x;
  const int qbase = blockIdx.y * 128;
  const __bf16* qp = q + (size_t)bh * S_LEN * D_DIM;
  const __bf16* kp = k + (size_t)bh * S_LEN * D_DIM;
  const __bf16* vp = v + (size_t)bh * S_LEN * D_DIM;
  __bf16* op = o + (size_t)bh * S_LEN * D_DIM;

  // Q^T B-fragments: lane needs Q[qrow][kc*16 + h*8 + i]
  const int qrow = qbase + wave * 32 + ql;
  bf16x8 qf[8];
#pragma unroll
  for (int kc = 0; kc < 8; ++kc)
    qf[kc] = *reinterpret_cast<const bf16x8*>(
        qp + (size_t)qrow * D_DIM + kc * 16 + h * 8);

  floatx16 ot[4];  // O^T accumulator: 4 d-blocks of 32
#pragma unroll
  for (int d = 0; d < 4; ++d)
#pragma unroll
    for (int r = 0; r < 16; ++r) ot[d][r] = 0.f;
  float m_r = -1e30f, l_r = 0.f;  // log2-domain running max / denom

  // staging map: pair-rows. pr = (tid>>4)*2 in {0..30}, ce = (tid&15)*8.
  // Each thread stages kv rows {pr, pr+1, pr+32, pr+33} of K and V.
  const int pr = (tid >> 4) * 2;
  const int ce = (tid & 15) * 8;

  // prologue: stage tile 0 into buf 0
  {
    const __bf16* kr = kp + (size_t)pr * D_DIM + ce;
    const __bf16* vr = vp + (size_t)pr * D_DIM + ce;
    bf16x8 kA0 = *reinterpret_cast<const bf16x8*>(kr);
    bf16x8 kA1 = *reinterpret_cast<const bf16x8*>(kr + D_DIM);
    bf16x8 kB0 = *reinterpret_cast<const bf16x8*>(kr + 32 * D_DIM);
    bf16x8 kB1 = *reinterpret_cast<const bf16x8*>(kr + 33 * D_DIM);
    union { bf16x8 v8; unsigned short s[8]; } vA0, vA1, vB0, vB1;
    vA0.v8 = *reinterpret_cast<const bf16x8*>(vr);
    vA1.v8 = *reinterpret_cast<const bf16x8*>(vr + D_DIM);
    vB0.v8 = *reinterpret_cast<const bf16x8*>(vr + 32 * D_DIM);
    vB1.v8 = *reinterpret_cast<const bf16x8*>(vr + 33 * D_DIM);
    *reinterpret_cast<bf16x8*>(Klb + swz(pr, pr * 256u + ce * 2u)) = kA0;
    *reinterpret_cast<bf16x8*>(Klb + swz(pr + 1, (pr + 1) * 256u + ce * 2u)) = kA1;
    *reinterpret_cast<bf16x8*>(Klb + swz(pr + 32, (pr + 32) * 256u + ce * 2u)) = kB0;
    *reinterpret_cast<bf16x8*>(Klb + swz(pr + 33, (pr + 33) * 256u + ce * 2u)) = kB1;
#pragma unroll
    for (int e = 0; e < 8; ++e) {
      int d = ce + e;
      unsigned w0 = (unsigned)vA0.s[e] | ((unsigned)vA1.s[e] << 16);
      unsigned w1 = (unsigned)vB0.s[e] | ((unsigned)vB1.s[e] << 16);
      *reinterpret_cast<unsigned*>(Vtb + swz(d, d * 128u + pr * 2u)) = w0;
      *reinterpret_cast<unsigned*>(Vtb + swz(d, d * 128u + (pr + 32) * 2u)) = w1;
    }
  }

  for (int t = 0; t < NKV; ++t) {
    const unsigned cb = (unsigned)(t & 1) * 16384u;
    const bool hn = (t + 1 < NKV);
    bf16x8 kA0, kA1, kB0, kB1;
    union { bf16x8 v8; unsigned short s[8]; } vA0, vA1, vB0, vB1;
    if (hn) {  // issue next-tile global loads; latency hides under compute
      const __bf16* kr = kp + ((size_t)(t + 1) * KVB + pr) * D_DIM + ce;
      const __bf16* vr = vp + ((size_t)(t + 1) * KVB + pr) * D_DIM + ce;
      kA0 = *reinterpret_cast<const bf16x8*>(kr);
      kA1 = *reinterpret_cast<const bf16x8*>(kr + D_DIM);
      kB0 = *reinterpret_cast<const bf16x8*>(kr + 32 * D_DIM);
      kB1 = *reinterpret_cast<const bf16x8*>(kr + 33 * D_DIM);
      vA0.v8 = *reinterpret_cast<const bf16x8*>(vr);
      vA1.v8 = *reinterpret_cast<const bf16x8*>(vr + D_DIM);
      vB0.v8 = *reinterpret_cast<const bf16x8*>(vr + 32 * D_DIM);
      vB1.v8 = *reinterpret_cast<const bf16x8*>(vr + 33 * D_DIM);
    }
    __syncthreads();  // buf[cur] staged; previous tile's readers done

    // ---- QK^T: S^T[kv][q] ----
    floatx16 st[2];
#pragma unroll
    for (int kvh = 0; kvh < 2; ++kvh)
#pragma unroll
      for (int r = 0; r < 16; ++r) st[kvh][r] = 0.f;
#pragma unroll
    for (int kvh = 0; kvh < 2; ++kvh) {
      __builtin_amdgcn_s_setprio(1);
#pragma unroll
      for (int kc = 0; kc < 8; ++kc) {
        int row = kvh * 32 + ql;
        bf16x8 kf = *reinterpret_cast<const bf16x8*>(
            Klb + cb + swz(row, row * 256u + kc * 32u + h * 16u));
        st[kvh] = __builtin_amdgcn_mfma_f32_32x32x16_bf16(kf, qf[kc], st[kvh], 0, 0, 0);
      }
      __builtin_amdgcn_s_setprio(0);
    }

    // ---- softmax in exp2 domain; tree max; defer-rescale (T13) ----
    float t8[8];
#pragma unroll
    for (int i = 0; i < 8; ++i)
      t8[i] = fmaxf(fmaxf(st[0][i], st[0][i + 8]), fmaxf(st[1][i], st[1][i + 8]));
    float pmax = fmaxf(fmaxf(fmaxf(t8[0], t8[4]), fmaxf(t8[1], t8[5])),
                       fmaxf(fmaxf(t8[2], t8[6]), fmaxf(t8[3], t8[7])));
    pmax = fmaxf(pmax, __shfl_xor(pmax, 32));
    if (!__all(pmax - m_r <= 8.0f)) {
      float mnew = fmaxf(m_r, pmax);
      float sc_f = exp2f(m_r - mnew);
      m_r = mnew;
      l_r *= sc_f;
#pragma unroll
      for (int d = 0; d < 4; ++d)
#pragma unroll
        for (int r = 0; r < 16; ++r) ot[d][r] *= sc_f;
    }
#pragma unroll
    for (int kvh = 0; kvh < 2; ++kvh)
#pragma unroll
      for (int r = 0; r < 16; ++r)
        st[kvh][r] = exp2f(st[kvh][r] - m_r);
    float s8[8];
#pragma unroll
    for (int i = 0; i < 8; ++i)
      s8[i] = (st[0][i] + st[0][i + 8]) + (st[1][i] + st[1][i + 8]);
    float psum = ((s8[0] + s8[4]) + (s8[1] + s8[5])) +
                 ((s8[2] + s8[6]) + (s8[3] + s8[7]));
    psum += __shfl_xor(psum, 32);
    l_r += psum;

    // ---- P^T B-fragments in-register + PV ----
#pragma unroll
    for (int ks = 0; ks < 4; ++ks) {
      const int kvh = ks >> 1;
      const int r2a = (2 * ks) & 3;
      const int r2b = r2a + 1;
      unsigned a0 = pack2(st[kvh][r2a * 4 + 0], st[kvh][r2a * 4 + 1]);
      unsigned a1 = pack2(st[kvh][r2a * 4 + 2], st[kvh][r2a * 4 + 3]);
      unsigned b0 = pack2(st[kvh][r2b * 4 + 0], st[kvh][r2b * 4 + 1]);
      unsigned b1 = pack2(st[kvh][r2b * 4 + 2], st[kvh][r2b * 4 + 3]);
      unsigned a0x = __shfl_xor(a0, 32), a1x = __shfl_xor(a1, 32);
      unsigned b0x = __shfl_xor(b0, 32), b1x = __shfl_xor(b1, 32);
      union { unsigned u[4]; bf16x8 v8; } pw;
      pw.u[0] = h ? b0x : a0;
      pw.u[1] = h ? b1x : a1;
      pw.u[2] = h ? b0 : a0x;
      pw.u[3] = h ? b1 : a1x;
      __builtin_amdgcn_s_setprio(1);
#pragma unroll
      for (int db = 0; db < 4; ++db) {
        int row = db * 32 + ql;
        bf16x8 vf = *reinterpret_cast<const bf16x8*>(
            Vtb + cb + swz(row, row * 128u + ks * 32u + h * 16u));
        ot[db] = __builtin_amdgcn_mfma_f32_32x32x16_bf16(vf, pw.v8, ot[db], 0, 0, 0);
      }
      __builtin_amdgcn_s_setprio(0);
    }

    // ---- write staged tile t+1 into buf[nxt] ----
    if (hn) {
      const unsigned nb = cb ^ 16384u;
      *reinterpret_cast<bf16x8*>(Klb + nb + swz(pr, pr * 256u + ce * 2u)) = kA0;
      *reinterpret_cast<bf16x8*>(Klb + nb + swz(pr + 1, (pr + 1) * 256u + ce * 2u)) = kA1;
      *reinterpret_cast<bf16x8*>(Klb + nb + swz(pr + 32, (pr + 32) * 256u + ce * 2u)) = kB0;
      *reinterpret_cast<bf16x8*>(Klb + nb + swz(pr + 33, (pr + 33) * 256u + ce * 2u)) = kB1;
#pragma unroll
      for (int e = 0; e < 8; ++e) {
        int d = ce + e;
        unsigned w0 = (unsigned)vA0.s[e] | ((unsigned)vA1.s[e] << 16);
        unsigned w1 = (unsigned)vB0.s[e] | ((unsigned)vB1.s[e] << 16);
        *reinterpret_cast<unsigned*>(Vtb + nb + swz(d, d * 128u + pr * 2u)) = w0;
        *reinterpret_cast<unsigned*>(Vtb + nb + swz(d, d * 128u + (pr + 32) * 2u)) = w1;
      }
    }
  }

  // ---- epilogue: O^T -> LDS transpose -> coalesced stores ----
  __syncthreads();  // done with K/V LDS; reuse as O tile [128 rows][256 B]
  const float inv_l = 1.0f / l_r;
  const int qloc = wave * 32 + ql;
#pragma unroll
  for (int db = 0; db < 4; ++db)
#pragma unroll
    for (int r = 0; r < 16; ++r) {
      int d = db * 32 + (r & 3) + 8 * (r >> 2) + 4 * h;
      *reinterpret_cast<__bf16*>(smem + swz(qloc, qloc * 256u + d * 2u)) =
          (__bf16)(ot[db][r] * inv_l);
    }
  __syncthreads();
#pragma unroll
  for (int it = 0; it < 8; ++it) {
    int r = tid >> 1;                  // 0..127
    int c = (tid & 1) * 64 + it * 8;   // element col
    bf16x8 val = *reinterpret_cast<const bf16x8*>(smem + swz(r, r * 256u + c * 2u));
    *reinterpret_cast<bf16x8*>(op + (size_t)(qbase + r) * D_DIM + c) = val;
  }
}

// ---------------------------------------------------------------------------
extern "C" void kernel_launch(void* const* d_in, const int* in_sizes, int n_in,
                              void* d_out, int out_size, void* d_ws, size_t ws_size,
                              hipStream_t stream) {
  const float* query = (const float*)d_in[0];
  const float* key_  = (const float*)d_in[1];
  const float* value = (const float*)d_in[2];
  const float* Wq = (const float*)d_in[3];
  const float* bq = (const float*)d_in[4];
  const float* Wk = (const float*)d_in[5];
  const float* bk = (const float*)d_in[6];
  const float* Wv = (const float*)d_in[7];
  const float* bv = (const float*)d_in[8];
  const float* Wo = (const float*)d_in[9];
  const float* bo = (const float*)d_in[10];

  // scratch: v + attn-out in d_ws; q + k scratch inside d_out (bf16, fully
  // overwritten by the final fp32 projection)
  __bf16* vws = (__bf16*)d_ws;
  __bf16* aws = vws + (size_t)NTOK * D_DIM;
  __bf16* qws = (__bf16*)d_out;
  __bf16* kws = qws + (size_t)NTOK * D_DIM;

  // q scale = log2(e)/sqrt(128): softmax runs in exp2 domain
  const float qscale = 0.1275174490036f;

  dim3 blk(256);
  proj_kernel<float, __bf16><<<NTOK / 64, blk, 0, stream>>>(query, Wq, bq, qws, qscale);
  proj_kernel<float, __bf16><<<NTOK / 64, blk, 0, stream>>>(key_, Wk, bk, kws, 1.0f);
  proj_kernel<float, __bf16><<<NTOK / 64, blk, 0, stream>>>(value, Wv, bv, vws, 1.0f);

  attn_kernel<<<dim3(32, 16), dim3(256), 0, stream>>>(qws, kws, vws, aws);

  proj_kernel<__bf16, float><<<NTOK / 64, blk, 0, stream>>>(aws, Wo, bo, (float*)d_out, 1.0f);
}

// Round 8
// 139.000 us; speedup vs baseline: 2.0741x; 1.1752x over previous
//
#include <hip/hip_runtime.h>
#include <hip/hip_bf16.h>
#include <type_traits>
#include <math.h>

typedef __bf16 bf16x8 __attribute__((ext_vector_type(8)));
typedef float floatx4 __attribute__((ext_vector_type(4)));
typedef float floatx16 __attribute__((ext_vector_type(16)));

#define S_LEN 2048
#define D_DIM 128
#define NTOK (2 * 16 * 2048)  // B*H*S = 65536 rows
#define KVB 64
#define NKV (S_LEN / KVB)     // 32 kv tiles

// ---------------------------------------------------------------------------
// proj body (shared): y[r,e] = (sum_d x[r,d] * W[e,d] + b[e]) * out_scale
// ---------------------------------------------------------------------------
template <typename TIN, typename TOUT>
__device__ __forceinline__ void proj_body(
    const TIN* __restrict__ x, const float* __restrict__ W,
    const float* __restrict__ b, TOUT* __restrict__ y, float out_scale,
    int rbase, __bf16 (*Wl)[128]) {
  const int tid = threadIdx.x;
  const int wave = tid >> 6, lane = tid & 63;
  const int g = lane >> 4, lr = lane & 15;

  for (int it = 0; it < 16; ++it) {
    int lin = it * 1024 + tid * 4;
    float4 w4 = *reinterpret_cast<const float4*>(W + lin);
    int r = lin >> 7, c = lin & 127;
    Wl[r][c]     = (__bf16)w4.x;
    Wl[r][c + 1] = (__bf16)w4.y;
    Wl[r][c + 2] = (__bf16)w4.z;
    Wl[r][c + 3] = (__bf16)w4.w;
  }
  __syncthreads();

  const int arow = rbase + wave * 16 + lr;

  floatx4 acc[8];
  for (int i = 0; i < 8; ++i) acc[i] = floatx4{0.f, 0.f, 0.f, 0.f};

  for (int kc = 0; kc < 4; ++kc) {
    bf16x8 af;
    const TIN* xp = x + (size_t)arow * D_DIM + kc * 32 + g * 8;
    if constexpr (std::is_same<TIN, float>::value) {
      float4 f0 = *reinterpret_cast<const float4*>(xp);
      float4 f1 = *reinterpret_cast<const float4*>(xp + 4);
      af[0] = (__bf16)f0.x; af[1] = (__bf16)f0.y;
      af[2] = (__bf16)f0.z; af[3] = (__bf16)f0.w;
      af[4] = (__bf16)f1.x; af[5] = (__bf16)f1.y;
      af[6] = (__bf16)f1.z; af[7] = (__bf16)f1.w;
    } else {
      af = *reinterpret_cast<const bf16x8*>(xp);
    }
    for (int nt = 0; nt < 8; ++nt) {
      bf16x8 wf = *reinterpret_cast<const bf16x8*>(&Wl[nt * 16 + lr][kc * 32 + g * 8]);
      acc[nt] = __builtin_amdgcn_mfma_f32_16x16x32_bf16(af, wf, acc[nt], 0, 0, 0);
    }
  }

  for (int nt = 0; nt < 8; ++nt) {
    int e = nt * 16 + lr;
    float be = b[e];
    for (int j = 0; j < 4; ++j) {
      int row = rbase + wave * 16 + g * 4 + j;
      float val = (acc[nt][j] + be) * out_scale;
      y[(size_t)row * D_DIM + e] = (TOUT)val;
    }
  }
}

// fused Q/K/V projection: blockIdx.y selects which of the three
__global__ __launch_bounds__(256) void qkv_proj_kernel(
    const float* __restrict__ xq, const float* __restrict__ xk,
    const float* __restrict__ xv, const float* __restrict__ Wq,
    const float* __restrict__ Wk, const float* __restrict__ Wv,
    const float* __restrict__ bq, const float* __restrict__ bk,
    const float* __restrict__ bv, __bf16* yq, __bf16* yk, __bf16* yv,
    float qscale) {
  __shared__ alignas(16) __bf16 Wl[128][128];
  const int which = blockIdx.y;
  const float* x = which == 0 ? xq : which == 1 ? xk : xv;
  const float* W = which == 0 ? Wq : which == 1 ? Wk : Wv;
  const float* b = which == 0 ? bq : which == 1 ? bk : bv;
  __bf16* y = which == 0 ? yq : which == 1 ? yk : yv;
  float sc = which == 0 ? qscale : 1.0f;
  proj_body<float, __bf16>(x, W, b, y, sc, blockIdx.x * 64, Wl);
}

__global__ __launch_bounds__(256) void o_proj_kernel(
    const __bf16* __restrict__ x, const float* __restrict__ W,
    const float* __restrict__ b, float* __restrict__ y) {
  __shared__ alignas(16) __bf16 Wl[128][128];
  proj_body<__bf16, float>(x, W, b, y, 1.0f, blockIdx.x * 64, Wl);
}

// ---------------------------------------------------------------------------
// LDS XOR swizzle: flips byte-offset bits 4..6 by (row ^ row>>3) & 7.
// ---------------------------------------------------------------------------
__device__ __forceinline__ unsigned swz(int row, unsigned byteoff) {
  return byteoff ^ (((unsigned)(row ^ (row >> 3)) & 7u) << 4);
}

__device__ __forceinline__ unsigned pack2(float lo, float hi) {
  union { __bf16 h[2]; unsigned u; } r;
  r.h[0] = (__bf16)lo; r.h[1] = (__bf16)hi;
  return r.u;
}

// ---------------------------------------------------------------------------
// attn_kernel v8: 4 waves x 32 q, 2 blocks/CU, swapped 32x32x16 QK^T,
// in-register exp2-domain softmax, T13 defer-rescale, in-register P^T,
// prefetch issued AFTER the barrier (barrier's vmcnt(0) drain never waits
// on it; loads consumed at loop tail under accumulated compute latency).
// P^T cross-half exchange via __builtin_amdgcn_permlane32_swap (compiler
// handles gfx950 permlane hazard wait-states; hand-written asm in r6/r7
// violated them -> wrong lanes). Fallback to v5-proven shfl+select.
// ---------------------------------------------------------------------------
__global__ __launch_bounds__(256, 2) void attn_kernel(
    const __bf16* __restrict__ q, const __bf16* __restrict__ k,
    const __bf16* __restrict__ v, __bf16* __restrict__ o) {
  __shared__ alignas(16) unsigned char smem[65536];
  unsigned char* Klb = smem;            // [2][64 rows * 256 B]  (32 KB)
  unsigned char* Vtb = smem + 32768;    // [2][128 rows * 128 B] (32 KB)

  const int tid = threadIdx.x;
  const int wave = tid >> 6, lane = tid & 63;
  const int ql = lane & 31;
  const int h = lane >> 5;

  const int bh = blockIdx.x;
  const int qbase = blockIdx.y * 128;
  const __bf16* qp = q + (size_t)bh * S_LEN * D_DIM;
  const __bf16* kp = k + (size_t)bh * S_LEN * D_DIM;
  const __bf16* vp = v + (size_t)bh * S_LEN * D_DIM;
  __bf16* op = o + (size_t)bh * S_LEN * D_DIM;

  // Q^T B-fragments
  const int qrow = qbase + wave * 32 + ql;
  bf16x8 qf[8];
#pragma unroll
  for (int kc = 0; kc < 8; ++kc)
    qf[kc] = *reinterpret_cast<const bf16x8*>(
        qp + (size_t)qrow * D_DIM + kc * 16 + h * 8);

  floatx16 ot[4];
#pragma unroll
  for (int d = 0; d < 4; ++d)
#pragma unroll
    for (int r = 0; r < 16; ++r) ot[d][r] = 0.f;
  float m_r = -1e30f, l_r = 0.f;

  // staging map: pair-rows. pr = (tid>>4)*2, ce = (tid&15)*8.
  const int pr = (tid >> 4) * 2;
  const int ce = (tid & 15) * 8;

  // prologue: stage tile 0 into buf 0
  {
    const __bf16* kr = kp + (size_t)pr * D_DIM + ce;
    const __bf16* vr = vp + (size_t)pr * D_DIM + ce;
    bf16x8 kA0 = *reinterpret_cast<const bf16x8*>(kr);
    bf16x8 kA1 = *reinterpret_cast<const bf16x8*>(kr + D_DIM);
    bf16x8 kB0 = *reinterpret_cast<const bf16x8*>(kr + 32 * D_DIM);
    bf16x8 kB1 = *reinterpret_cast<const bf16x8*>(kr + 33 * D_DIM);
    union { bf16x8 v8; unsigned short s[8]; } vA0, vA1, vB0, vB1;
    vA0.v8 = *reinterpret_cast<const bf16x8*>(vr);
    vA1.v8 = *reinterpret_cast<const bf16x8*>(vr + D_DIM);
    vB0.v8 = *reinterpret_cast<const bf16x8*>(vr + 32 * D_DIM);
    vB1.v8 = *reinterpret_cast<const bf16x8*>(vr + 33 * D_DIM);
    *reinterpret_cast<bf16x8*>(Klb + swz(pr, pr * 256u + ce * 2u)) = kA0;
    *reinterpret_cast<bf16x8*>(Klb + swz(pr + 1, (pr + 1) * 256u + ce * 2u)) = kA1;
    *reinterpret_cast<bf16x8*>(Klb + swz(pr + 32, (pr + 32) * 256u + ce * 2u)) = kB0;
    *reinterpret_cast<bf16x8*>(Klb + swz(pr + 33, (pr + 33) * 256u + ce * 2u)) = kB1;
#pragma unroll
    for (int e = 0; e < 8; ++e) {
      int d = ce + e;
      unsigned w0 = (unsigned)vA0.s[e] | ((unsigned)vA1.s[e] << 16);
      unsigned w1 = (unsigned)vB0.s[e] | ((unsigned)vB1.s[e] << 16);
      *reinterpret_cast<unsigned*>(Vtb + swz(d, d * 128u + pr * 2u)) = w0;
      *reinterpret_cast<unsigned*>(Vtb + swz(d, d * 128u + (pr + 32) * 2u)) = w1;
    }
  }

  for (int t = 0; t < NKV; ++t) {
    const unsigned cb = (unsigned)(t & 1) * 16384u;
    const bool hn = (t + 1 < NKV);

    __syncthreads();  // buf[cur] staged; previous tile's readers done.
                      // Prefetch is issued AFTER this barrier so the
                      // barrier's vmcnt(0) drain never waits on it.

    bf16x8 kA0, kA1, kB0, kB1;
    union { bf16x8 v8; unsigned short s[8]; } vA0, vA1, vB0, vB1;
    if (hn) {  // issue next-tile global loads; consumed at loop tail
      const __bf16* kr = kp + ((size_t)(t + 1) * KVB + pr) * D_DIM + ce;
      const __bf16* vr = vp + ((size_t)(t + 1) * KVB + pr) * D_DIM + ce;
      kA0 = *reinterpret_cast<const bf16x8*>(kr);
      kA1 = *reinterpret_cast<const bf16x8*>(kr + D_DIM);
      kB0 = *reinterpret_cast<const bf16x8*>(kr + 32 * D_DIM);
      kB1 = *reinterpret_cast<const bf16x8*>(kr + 33 * D_DIM);
      vA0.v8 = *reinterpret_cast<const bf16x8*>(vr);
      vA1.v8 = *reinterpret_cast<const bf16x8*>(vr + D_DIM);
      vB0.v8 = *reinterpret_cast<const bf16x8*>(vr + 32 * D_DIM);
      vB1.v8 = *reinterpret_cast<const bf16x8*>(vr + 33 * D_DIM);
    }

    // ---- QK^T: S^T[kv][q], st[0]/st[1] interleaved ----
    floatx16 st[2];
#pragma unroll
    for (int kvh = 0; kvh < 2; ++kvh)
#pragma unroll
      for (int r = 0; r < 16; ++r) st[kvh][r] = 0.f;
    __builtin_amdgcn_s_setprio(1);
#pragma unroll
    for (int kc = 0; kc < 8; ++kc) {
      bf16x8 kf0 = *reinterpret_cast<const bf16x8*>(
          Klb + cb + swz(ql, ql * 256u + kc * 32u + h * 16u));
      bf16x8 kf1 = *reinterpret_cast<const bf16x8*>(
          Klb + cb + swz(32 + ql, (32 + ql) * 256u + kc * 32u + h * 16u));
      st[0] = __builtin_amdgcn_mfma_f32_32x32x16_bf16(kf0, qf[kc], st[0], 0, 0, 0);
      st[1] = __builtin_amdgcn_mfma_f32_32x32x16_bf16(kf1, qf[kc], st[1], 0, 0, 0);
    }
    __builtin_amdgcn_s_setprio(0);

    // ---- softmax (exp2 domain), tree max/sum, T13 defer-rescale ----
    float t8[8];
#pragma unroll
    for (int i = 0; i < 8; ++i)
      t8[i] = fmaxf(fmaxf(st[0][i], st[0][i + 8]), fmaxf(st[1][i], st[1][i + 8]));
    float pmax = fmaxf(fmaxf(fmaxf(t8[0], t8[4]), fmaxf(t8[1], t8[5])),
                       fmaxf(fmaxf(t8[2], t8[6]), fmaxf(t8[3], t8[7])));
    pmax = fmaxf(pmax, __shfl_xor(pmax, 32));
    if (!__all(pmax - m_r <= 8.0f)) {
      float mnew = fmaxf(m_r, pmax);
      float sc_f = __builtin_amdgcn_exp2f(m_r - mnew);
      m_r = mnew;
      l_r *= sc_f;
#pragma unroll
      for (int d = 0; d < 4; ++d)
#pragma unroll
        for (int r = 0; r < 16; ++r) ot[d][r] *= sc_f;
    }
#pragma unroll
    for (int kvh = 0; kvh < 2; ++kvh)
#pragma unroll
      for (int r = 0; r < 16; ++r)
        st[kvh][r] = __builtin_amdgcn_exp2f(st[kvh][r] - m_r);
    float s8[8];
#pragma unroll
    for (int i = 0; i < 8; ++i)
      s8[i] = (st[0][i] + st[0][i + 8]) + (st[1][i] + st[1][i + 8]);
    float psum = ((s8[0] + s8[4]) + (s8[1] + s8[5])) +
                 ((s8[2] + s8[6]) + (s8[3] + s8[7]));
    psum += __shfl_xor(psum, 32);
    l_r += psum;

    // ---- P^T B-fragments (cross-half exchange) + PV ----
#pragma unroll
    for (int ks = 0; ks < 4; ++ks) {
      const int kvh = ks >> 1;
      const int r2a = (2 * ks) & 3;
      const int r2b = r2a + 1;
      unsigned a0 = pack2(st[kvh][r2a * 4 + 0], st[kvh][r2a * 4 + 1]);
      unsigned a1 = pack2(st[kvh][r2a * 4 + 2], st[kvh][r2a * 4 + 3]);
      unsigned b0 = pack2(st[kvh][r2b * 4 + 0], st[kvh][r2b * 4 + 1]);
      unsigned b1 = pack2(st[kvh][r2b * 4 + 2], st[kvh][r2b * 4 + 3]);
      union { unsigned u[4]; bf16x8 v8; } pw;
#if __has_builtin(__builtin_amdgcn_permlane32_swap)
      // r[0] = {a[0:31], b[0:31]}, r[1] = {a[32:63], b[32:63]} -> for every
      // lane: needed {own-group, partner-group} pair lands in (r0, r1).
      {
        auto r0 = __builtin_amdgcn_permlane32_swap(a0, b0, false, false);
        auto r1 = __builtin_amdgcn_permlane32_swap(a1, b1, false, false);
        pw.u[0] = r0[0];  // kv offsets 0-1 of group 2ks+h
        pw.u[1] = r1[0];  // offsets 2-3
        pw.u[2] = r0[1];  // offsets 4-5
        pw.u[3] = r1[1];  // offsets 6-7
      }
#else
      // v5-proven fallback: shfl + select
      {
        unsigned a0x = __shfl_xor(a0, 32), a1x = __shfl_xor(a1, 32);
        unsigned b0x = __shfl_xor(b0, 32), b1x = __shfl_xor(b1, 32);
        pw.u[0] = h ? b0x : a0;
        pw.u[1] = h ? b1x : a1;
        pw.u[2] = h ? b0 : a0x;
        pw.u[3] = h ? b1 : a1x;
      }
#endif
      __builtin_amdgcn_s_setprio(1);
#pragma unroll
      for (int db = 0; db < 4; ++db) {
        int row = db * 32 + ql;
        bf16x8 vf = *reinterpret_cast<const bf16x8*>(
            Vtb + cb + swz(row, row * 128u + ks * 32u + h * 16u));
        ot[db] = __builtin_amdgcn_mfma_f32_32x32x16_bf16(vf, pw.v8, ot[db], 0, 0, 0);
      }
      __builtin_amdgcn_s_setprio(0);
    }

    // ---- write staged tile t+1 into buf[nxt] (vmcnt wait lands here) ----
    if (hn) {
      const unsigned nb = cb ^ 16384u;
      *reinterpret_cast<bf16x8*>(Klb + nb + swz(pr, pr * 256u + ce * 2u)) = kA0;
      *reinterpret_cast<bf16x8*>(Klb + nb + swz(pr + 1, (pr + 1) * 256u + ce * 2u)) = kA1;
      *reinterpret_cast<bf16x8*>(Klb + nb + swz(pr + 32, (pr + 32) * 256u + ce * 2u)) = kB0;
      *reinterpret_cast<bf16x8*>(Klb + nb + swz(pr + 33, (pr + 33) * 256u + ce * 2u)) = kB1;
#pragma unroll
      for (int e = 0; e < 8; ++e) {
        int d = ce + e;
        unsigned w0 = (unsigned)vA0.s[e] | ((unsigned)vA1.s[e] << 16);
        unsigned w1 = (unsigned)vB0.s[e] | ((unsigned)vB1.s[e] << 16);
        *reinterpret_cast<unsigned*>(Vtb + nb + swz(d, d * 128u + pr * 2u)) = w0;
        *reinterpret_cast<unsigned*>(Vtb + nb + swz(d, d * 128u + (pr + 32) * 2u)) = w1;
      }
    }
  }

  // ---- epilogue: O^T -> LDS transpose -> coalesced stores ----
  __syncthreads();
  const float inv_l = 1.0f / l_r;
  const int qloc = wave * 32 + ql;
#pragma unroll
  for (int db = 0; db < 4; ++db)
#pragma unroll
    for (int r = 0; r < 16; ++r) {
      int d = db * 32 + (r & 3) + 8 * (r >> 2) + 4 * h;
      *reinterpret_cast<__bf16*>(smem + swz(qloc, qloc * 256u + d * 2u)) =
          (__bf16)(ot[db][r] * inv_l);
    }
  __syncthreads();
#pragma unroll
  for (int it = 0; it < 8; ++it) {
    int r = tid >> 1;
    int c = (tid & 1) * 64 + it * 8;
    bf16x8 val = *reinterpret_cast<const bf16x8*>(smem + swz(r, r * 256u + c * 2u));
    *reinterpret_cast<bf16x8*>(op + (size_t)(qbase + r) * D_DIM + c) = val;
  }
}

// ---------------------------------------------------------------------------
extern "C" void kernel_launch(void* const* d_in, const int* in_sizes, int n_in,
                              void* d_out, int out_size, void* d_ws, size_t ws_size,
                              hipStream_t stream) {
  const float* query = (const float*)d_in[0];
  const float* key_  = (const float*)d_in[1];
  const float* value = (const float*)d_in[2];
  const float* Wq = (const float*)d_in[3];
  const float* bq = (const float*)d_in[4];
  const float* Wk = (const float*)d_in[5];
  const float* bk = (const float*)d_in[6];
  const float* Wv = (const float*)d_in[7];
  const float* bv = (const float*)d_in[8];
  const float* Wo = (const float*)d_in[9];
  const float* bo = (const float*)d_in[10];

  // scratch: v + attn-out in d_ws; q + k scratch inside d_out (bf16, fully
  // overwritten by the final fp32 projection)
  __bf16* vws = (__bf16*)d_ws;
  __bf16* aws = vws + (size_t)NTOK * D_DIM;
  __bf16* qws = (__bf16*)d_out;
  __bf16* kws = qws + (size_t)NTOK * D_DIM;

  // q scale = log2(e)/sqrt(128): softmax runs in exp2 domain
  const float qscale = 0.1275174490036f;

  qkv_proj_kernel<<<dim3(NTOK / 64, 3), dim3(256), 0, stream>>>(
      query, key_, value, Wq, Wk, Wv, bq, bk, bv, qws, kws, vws, qscale);

  attn_kernel<<<dim3(32, 16), dim3(256), 0, stream>>>(qws, kws, vws, aws);

  o_proj_kernel<<<NTOK / 64, dim3(256), 0, stream>>>(aws, Wo, bo, (float*)d_out);
}

// Round 9
// 133.325 us; speedup vs baseline: 2.1624x; 1.0426x over previous
//
#include <hip/hip_runtime.h>
#include <hip/hip_bf16.h>
#include <type_traits>
#include <math.h>

typedef __bf16 bf16x8 __attribute__((ext_vector_type(8)));
typedef float floatx4 __attribute__((ext_vector_type(4)));
typedef float floatx16 __attribute__((ext_vector_type(16)));

#define S_LEN 2048
#define D_DIM 128
#define NTOK (2 * 16 * 2048)  // B*H*S = 65536 rows
#define KVB 64
#define NKV (S_LEN / KVB)     // 32 kv tiles

// ---------------------------------------------------------------------------
// proj body: stages W once, then processes 4 chunks of 64 rows.
// y[r,e] = (sum_d x[r,d] * W[e,d] + b[e]) * out_scale
// ---------------------------------------------------------------------------
template <typename TIN, typename TOUT>
__device__ __forceinline__ void proj_body4(
    const TIN* __restrict__ x, const float* __restrict__ W,
    const float* __restrict__ b, TOUT* __restrict__ y, float out_scale,
    int chunk0, __bf16 (*Wl)[128]) {
  const int tid = threadIdx.x;
  const int wave = tid >> 6, lane = tid & 63;
  const int g = lane >> 4, lr = lane & 15;

  for (int it = 0; it < 16; ++it) {
    int lin = it * 1024 + tid * 4;
    float4 w4 = *reinterpret_cast<const float4*>(W + lin);
    int r = lin >> 7, c = lin & 127;
    Wl[r][c]     = (__bf16)w4.x;
    Wl[r][c + 1] = (__bf16)w4.y;
    Wl[r][c + 2] = (__bf16)w4.z;
    Wl[r][c + 3] = (__bf16)w4.w;
  }
  __syncthreads();

  float be[8];
#pragma unroll
  for (int nt = 0; nt < 8; ++nt) be[nt] = b[nt * 16 + lr];

  for (int ch = 0; ch < 4; ++ch) {
    const int rbase = (chunk0 + ch) * 64;
    const int arow = rbase + wave * 16 + lr;

    floatx4 acc[8];
#pragma unroll
    for (int i = 0; i < 8; ++i) acc[i] = floatx4{0.f, 0.f, 0.f, 0.f};

#pragma unroll
    for (int kc = 0; kc < 4; ++kc) {
      bf16x8 af;
      const TIN* xp = x + (size_t)arow * D_DIM + kc * 32 + g * 8;
      if constexpr (std::is_same<TIN, float>::value) {
        float4 f0 = *reinterpret_cast<const float4*>(xp);
        float4 f1 = *reinterpret_cast<const float4*>(xp + 4);
        af[0] = (__bf16)f0.x; af[1] = (__bf16)f0.y;
        af[2] = (__bf16)f0.z; af[3] = (__bf16)f0.w;
        af[4] = (__bf16)f1.x; af[5] = (__bf16)f1.y;
        af[6] = (__bf16)f1.z; af[7] = (__bf16)f1.w;
      } else {
        af = *reinterpret_cast<const bf16x8*>(xp);
      }
#pragma unroll
      for (int nt = 0; nt < 8; ++nt) {
        bf16x8 wf = *reinterpret_cast<const bf16x8*>(&Wl[nt * 16 + lr][kc * 32 + g * 8]);
        acc[nt] = __builtin_amdgcn_mfma_f32_16x16x32_bf16(af, wf, acc[nt], 0, 0, 0);
      }
    }

#pragma unroll
    for (int nt = 0; nt < 8; ++nt) {
      int e = nt * 16 + lr;
#pragma unroll
      for (int j = 0; j < 4; ++j) {
        int row = rbase + wave * 16 + g * 4 + j;
        float val = (acc[nt][j] + be[nt]) * out_scale;
        y[(size_t)row * D_DIM + e] = (TOUT)val;
      }
    }
  }
}

// fused Q/K/V projection: blockIdx.y selects which of the three
__global__ __launch_bounds__(256) void qkv_proj_kernel(
    const float* __restrict__ xq, const float* __restrict__ xk,
    const float* __restrict__ xv, const float* __restrict__ Wq,
    const float* __restrict__ Wk, const float* __restrict__ Wv,
    const float* __restrict__ bq, const float* __restrict__ bk,
    const float* __restrict__ bv, __bf16* yq, __bf16* yk, __bf16* yv,
    float qscale) {
  __shared__ alignas(16) __bf16 Wl[128][128];
  const int which = blockIdx.y;
  const float* x = which == 0 ? xq : which == 1 ? xk : xv;
  const float* W = which == 0 ? Wq : which == 1 ? Wk : Wv;
  const float* b = which == 0 ? bq : which == 1 ? bk : bv;
  __bf16* y = which == 0 ? yq : which == 1 ? yk : yv;
  float sc = which == 0 ? qscale : 1.0f;
  proj_body4<float, __bf16>(x, W, b, y, sc, blockIdx.x * 4, Wl);
}

__global__ __launch_bounds__(256) void o_proj_kernel(
    const __bf16* __restrict__ x, const float* __restrict__ W,
    const float* __restrict__ b, float* __restrict__ y) {
  __shared__ alignas(16) __bf16 Wl[128][128];
  proj_body4<__bf16, float>(x, W, b, y, 1.0f, blockIdx.x * 4, Wl);
}

// ---------------------------------------------------------------------------
// LDS XOR swizzle: flips byte-offset bits 4..6 by (row ^ row>>3) & 7.
// ---------------------------------------------------------------------------
__device__ __forceinline__ unsigned swz(int row, unsigned byteoff) {
  return byteoff ^ (((unsigned)(row ^ (row >> 3)) & 7u) << 4);
}

__device__ __forceinline__ unsigned pack2(float lo, float hi) {
  union { __bf16 h[2]; unsigned u; } r;
  r.h[0] = (__bf16)lo; r.h[1] = (__bf16)hi;
  return r.u;
}

// ---------------------------------------------------------------------------
// attn_kernel v9 (= v8 + addressing hoist): 4 waves x 32 q, 2 blocks/CU,
// swapped 32x32x16 QK^T, in-register exp2-domain softmax, T13 defer-rescale,
// in-register P^T via permlane32_swap builtin, prefetch after barrier.
// NEW: all 52 swizzled LDS byte-offsets precomputed before the kv loop
// (they are loop-invariant); #pragma unroll 2 makes the 0/16384 buffer
// toggle a compile-time constant folded into ds offset immediates; running
// global pointers replace per-tile 64-bit address chains. ~200 VALU
// instr/wave/tile of recomputed addressing removed.
// K region: smem[0..32768) (two 16 KB buffers); V: smem[32768..65536).
// ---------------------------------------------------------------------------
__global__ __launch_bounds__(256, 2) void attn_kernel(
    const __bf16* __restrict__ q, const __bf16* __restrict__ k,
    const __bf16* __restrict__ v, __bf16* __restrict__ o) {
  __shared__ alignas(16) unsigned char smem[65536];

  const int tid = threadIdx.x;
  const int wave = tid >> 6, lane = tid & 63;
  const int ql = lane & 31;
  const int h = lane >> 5;

  const int bh = blockIdx.x;
  const int qbase = blockIdx.y * 128;
  const __bf16* qp = q + (size_t)bh * S_LEN * D_DIM;
  const __bf16* kp = k + (size_t)bh * S_LEN * D_DIM;
  const __bf16* vp = v + (size_t)bh * S_LEN * D_DIM;
  __bf16* op = o + (size_t)bh * S_LEN * D_DIM;

  // Q^T B-fragments
  const int qrow = qbase + wave * 32 + ql;
  bf16x8 qf[8];
#pragma unroll
  for (int kc = 0; kc < 8; ++kc)
    qf[kc] = *reinterpret_cast<const bf16x8*>(
        qp + (size_t)qrow * D_DIM + kc * 16 + h * 8);

  floatx16 ot[4];
#pragma unroll
  for (int d = 0; d < 4; ++d)
#pragma unroll
    for (int r = 0; r < 16; ++r) ot[d][r] = 0.f;
  float m_r = -1e30f, l_r = 0.f;

  // staging map: pair-rows. pr = (tid>>4)*2, ce = (tid&15)*8.
  const int pr = (tid >> 4) * 2;
  const int ce = (tid & 15) * 8;

  // ---- precomputed LDS byte-offsets (loop-invariant) ----
  unsigned ka[16];  // K reads: [kvh*8+kc]
#pragma unroll
  for (int kvh = 0; kvh < 2; ++kvh)
#pragma unroll
    for (int kc = 0; kc < 8; ++kc) {
      int row = kvh * 32 + ql;
      ka[kvh * 8 + kc] = swz(row, row * 256u + kc * 32u + h * 16u);
    }
  unsigned va[16];  // V reads: [ks*4+db]
#pragma unroll
  for (int ks = 0; ks < 4; ++ks)
#pragma unroll
    for (int db = 0; db < 4; ++db) {
      int row = db * 32 + ql;
      va[ks * 4 + db] = 32768u + swz(row, row * 128u + ks * 32u + h * 16u);
    }
  unsigned kw[4];   // K stage writes: rows pr, pr+1, pr+32, pr+33
  {
    int rows[4] = {pr, pr + 1, pr + 32, pr + 33};
#pragma unroll
    for (int i = 0; i < 4; ++i)
      kw[i] = swz(rows[i], rows[i] * 256u + ce * 2u);
  }
  unsigned vw[16];  // V stage writes: [e*2 + half], d = ce+e
#pragma unroll
  for (int e = 0; e < 8; ++e) {
    int d = ce + e;
    vw[e * 2]     = 32768u + swz(d, d * 128u + pr * 2u);
    vw[e * 2 + 1] = 32768u + swz(d, d * 128u + (pr + 32) * 2u);
  }

  // ---- prologue: stage tile 0 into buf 0 ----
  {
    const __bf16* kr = kp + (size_t)pr * D_DIM + ce;
    const __bf16* vr = vp + (size_t)pr * D_DIM + ce;
    bf16x8 kA0 = *reinterpret_cast<const bf16x8*>(kr);
    bf16x8 kA1 = *reinterpret_cast<const bf16x8*>(kr + D_DIM);
    bf16x8 kB0 = *reinterpret_cast<const bf16x8*>(kr + 32 * D_DIM);
    bf16x8 kB1 = *reinterpret_cast<const bf16x8*>(kr + 33 * D_DIM);
    union { bf16x8 v8; unsigned short s[8]; } vA0, vA1, vB0, vB1;
    vA0.v8 = *reinterpret_cast<const bf16x8*>(vr);
    vA1.v8 = *reinterpret_cast<const bf16x8*>(vr + D_DIM);
    vB0.v8 = *reinterpret_cast<const bf16x8*>(vr + 32 * D_DIM);
    vB1.v8 = *reinterpret_cast<const bf16x8*>(vr + 33 * D_DIM);
    *reinterpret_cast<bf16x8*>(smem + kw[0]) = kA0;
    *reinterpret_cast<bf16x8*>(smem + kw[1]) = kA1;
    *reinterpret_cast<bf16x8*>(smem + kw[2]) = kB0;
    *reinterpret_cast<bf16x8*>(smem + kw[3]) = kB1;
#pragma unroll
    for (int e = 0; e < 8; ++e) {
      unsigned w0 = (unsigned)vA0.s[e] | ((unsigned)vA1.s[e] << 16);
      unsigned w1 = (unsigned)vB0.s[e] | ((unsigned)vB1.s[e] << 16);
      *reinterpret_cast<unsigned*>(smem + vw[e * 2]) = w0;
      *reinterpret_cast<unsigned*>(smem + vw[e * 2 + 1]) = w1;
    }
  }

  // running prefetch pointers (tile t+1, rows pr / pr+32, col ce)
  const __bf16* krp = kp + ((size_t)KVB + pr) * D_DIM + ce;
  const __bf16* vrp = vp + ((size_t)KVB + pr) * D_DIM + ce;

#pragma unroll 2
  for (int t = 0; t < NKV; ++t) {
    const unsigned cb = (unsigned)(t & 1) * 16384u;  // const after unroll-2
    const bool hn = (t + 1 < NKV);

    __syncthreads();  // buf[cur] staged; previous tile's readers done.

    bf16x8 kA0, kA1, kB0, kB1;
    union { bf16x8 v8; unsigned short s[8]; } vA0, vA1, vB0, vB1;
    if (hn) {  // issue next-tile global loads; consumed at loop tail
      kA0 = *reinterpret_cast<const bf16x8*>(krp);
      kA1 = *reinterpret_cast<const bf16x8*>(krp + D_DIM);
      kB0 = *reinterpret_cast<const bf16x8*>(krp + 32 * D_DIM);
      kB1 = *reinterpret_cast<const bf16x8*>(krp + 33 * D_DIM);
      vA0.v8 = *reinterpret_cast<const bf16x8*>(vrp);
      vA1.v8 = *reinterpret_cast<const bf16x8*>(vrp + D_DIM);
      vB0.v8 = *reinterpret_cast<const bf16x8*>(vrp + 32 * D_DIM);
      vB1.v8 = *reinterpret_cast<const bf16x8*>(vrp + 33 * D_DIM);
      krp += (size_t)KVB * D_DIM;
      vrp += (size_t)KVB * D_DIM;
    }

    // ---- QK^T: S^T[kv][q], st[0]/st[1] interleaved ----
    floatx16 st[2];
#pragma unroll
    for (int kvh = 0; kvh < 2; ++kvh)
#pragma unroll
      for (int r = 0; r < 16; ++r) st[kvh][r] = 0.f;
    __builtin_amdgcn_s_setprio(1);
#pragma unroll
    for (int kc = 0; kc < 8; ++kc) {
      bf16x8 kf0 = *reinterpret_cast<const bf16x8*>(smem + cb + ka[kc]);
      bf16x8 kf1 = *reinterpret_cast<const bf16x8*>(smem + cb + ka[8 + kc]);
      st[0] = __builtin_amdgcn_mfma_f32_32x32x16_bf16(kf0, qf[kc], st[0], 0, 0, 0);
      st[1] = __builtin_amdgcn_mfma_f32_32x32x16_bf16(kf1, qf[kc], st[1], 0, 0, 0);
    }
    __builtin_amdgcn_s_setprio(0);

    // ---- softmax (exp2 domain), tree max/sum, T13 defer-rescale ----
    float t8[8];
#pragma unroll
    for (int i = 0; i < 8; ++i)
      t8[i] = fmaxf(fmaxf(st[0][i], st[0][i + 8]), fmaxf(st[1][i], st[1][i + 8]));
    float pmax = fmaxf(fmaxf(fmaxf(t8[0], t8[4]), fmaxf(t8[1], t8[5])),
                       fmaxf(fmaxf(t8[2], t8[6]), fmaxf(t8[3], t8[7])));
    pmax = fmaxf(pmax, __shfl_xor(pmax, 32));
    if (!__all(pmax - m_r <= 8.0f)) {
      float mnew = fmaxf(m_r, pmax);
      float sc_f = __builtin_amdgcn_exp2f(m_r - mnew);
      m_r = mnew;
      l_r *= sc_f;
#pragma unroll
      for (int d = 0; d < 4; ++d)
#pragma unroll
        for (int r = 0; r < 16; ++r) ot[d][r] *= sc_f;
    }
#pragma unroll
    for (int kvh = 0; kvh < 2; ++kvh)
#pragma unroll
      for (int r = 0; r < 16; ++r)
        st[kvh][r] = __builtin_amdgcn_exp2f(st[kvh][r] - m_r);
    float s8[8];
#pragma unroll
    for (int i = 0; i < 8; ++i)
      s8[i] = (st[0][i] + st[0][i + 8]) + (st[1][i] + st[1][i + 8]);
    float psum = ((s8[0] + s8[4]) + (s8[1] + s8[5])) +
                 ((s8[2] + s8[6]) + (s8[3] + s8[7]));
    psum += __shfl_xor(psum, 32);
    l_r += psum;

    // ---- P^T B-fragments (cross-half exchange) + PV ----
#pragma unroll
    for (int ks = 0; ks < 4; ++ks) {
      const int kvh = ks >> 1;
      const int r2a = (2 * ks) & 3;
      const int r2b = r2a + 1;
      unsigned a0 = pack2(st[kvh][r2a * 4 + 0], st[kvh][r2a * 4 + 1]);
      unsigned a1 = pack2(st[kvh][r2a * 4 + 2], st[kvh][r2a * 4 + 3]);
      unsigned b0 = pack2(st[kvh][r2b * 4 + 0], st[kvh][r2b * 4 + 1]);
      unsigned b1 = pack2(st[kvh][r2b * 4 + 2], st[kvh][r2b * 4 + 3]);
      union { unsigned u[4]; bf16x8 v8; } pw;
#if __has_builtin(__builtin_amdgcn_permlane32_swap)
      {
        auto r0 = __builtin_amdgcn_permlane32_swap(a0, b0, false, false);
        auto r1 = __builtin_amdgcn_permlane32_swap(a1, b1, false, false);
        pw.u[0] = r0[0];  // kv offsets 0-1 of group 2ks+h
        pw.u[1] = r1[0];  // offsets 2-3
        pw.u[2] = r0[1];  // offsets 4-5
        pw.u[3] = r1[1];  // offsets 6-7
      }
#else
      {
        unsigned a0x = __shfl_xor(a0, 32), a1x = __shfl_xor(a1, 32);
        unsigned b0x = __shfl_xor(b0, 32), b1x = __shfl_xor(b1, 32);
        pw.u[0] = h ? b0x : a0;
        pw.u[1] = h ? b1x : a1;
        pw.u[2] = h ? b0 : a0x;
        pw.u[3] = h ? b1 : a1x;
      }
#endif
      __builtin_amdgcn_s_setprio(1);
#pragma unroll
      for (int db = 0; db < 4; ++db) {
        bf16x8 vf = *reinterpret_cast<const bf16x8*>(smem + cb + va[ks * 4 + db]);
        ot[db] = __builtin_amdgcn_mfma_f32_32x32x16_bf16(vf, pw.v8, ot[db], 0, 0, 0);
      }
      __builtin_amdgcn_s_setprio(0);
    }

    // ---- write staged tile t+1 into buf[nxt] (vmcnt wait lands here) ----
    if (hn) {
      const unsigned nb = cb ^ 16384u;  // const after unroll-2
      *reinterpret_cast<bf16x8*>(smem + nb + kw[0]) = kA0;
      *reinterpret_cast<bf16x8*>(smem + nb + kw[1]) = kA1;
      *reinterpret_cast<bf16x8*>(smem + nb + kw[2]) = kB0;
      *reinterpret_cast<bf16x8*>(smem + nb + kw[3]) = kB1;
#pragma unroll
      for (int e = 0; e < 8; ++e) {
        unsigned w0 = (unsigned)vA0.s[e] | ((unsigned)vA1.s[e] << 16);
        unsigned w1 = (unsigned)vB0.s[e] | ((unsigned)vB1.s[e] << 16);
        *reinterpret_cast<unsigned*>(smem + nb + vw[e * 2]) = w0;
        *reinterpret_cast<unsigned*>(smem + nb + vw[e * 2 + 1]) = w1;
      }
    }
  }

  // ---- epilogue: O^T -> LDS transpose -> coalesced stores ----
  __syncthreads();
  const float inv_l = 1.0f / l_r;
  const int qloc = wave * 32 + ql;
#pragma unroll
  for (int db = 0; db < 4; ++db)
#pragma unroll
    for (int r = 0; r < 16; ++r) {
      int d = db * 32 + (r & 3) + 8 * (r >> 2) + 4 * h;
      *reinterpret_cast<__bf16*>(smem + swz(qloc, qloc * 256u + d * 2u)) =
          (__bf16)(ot[db][r] * inv_l);
    }
  __syncthreads();
#pragma unroll
  for (int it = 0; it < 8; ++it) {
    int r = tid >> 1;
    int c = (tid & 1) * 64 + it * 8;
    bf16x8 val = *reinterpret_cast<const bf16x8*>(smem + swz(r, r * 256u + c * 2u));
    *reinterpret_cast<bf16x8*>(op + (size_t)(qbase + r) * D_DIM + c) = val;
  }
}

// ---------------------------------------------------------------------------
extern "C" void kernel_launch(void* const* d_in, const int* in_sizes, int n_in,
                              void* d_out, int out_size, void* d_ws, size_t ws_size,
                              hipStream_t stream) {
  const float* query = (const float*)d_in[0];
  const float* key_  = (const float*)d_in[1];
  const float* value = (const float*)d_in[2];
  const float* Wq = (const float*)d_in[3];
  const float* bq = (const float*)d_in[4];
  const float* Wk = (const float*)d_in[5];
  const float* bk = (const float*)d_in[6];
  const float* Wv = (const float*)d_in[7];
  const float* bv = (const float*)d_in[8];
  const float* Wo = (const float*)d_in[9];
  const float* bo = (const float*)d_in[10];

  // scratch: v + attn-out in d_ws; q + k scratch inside d_out (bf16, fully
  // overwritten by the final fp32 projection)
  __bf16* vws = (__bf16*)d_ws;
  __bf16* aws = vws + (size_t)NTOK * D_DIM;
  __bf16* qws = (__bf16*)d_out;
  __bf16* kws = qws + (size_t)NTOK * D_DIM;

  // q scale = log2(e)/sqrt(128): softmax runs in exp2 domain
  const float qscale = 0.1275174490036f;

  qkv_proj_kernel<<<dim3(NTOK / 256, 3), dim3(256), 0, stream>>>(
      query, key_, value, Wq, Wk, Wv, bq, bk, bv, qws, kws, vws, qscale);

  attn_kernel<<<dim3(32, 16), dim3(256), 0, stream>>>(qws, kws, vws, aws);

  o_proj_kernel<<<NTOK / 256, dim3(256), 0, stream>>>(aws, Wo, bo, (float*)d_out);
}